// Round 4
// baseline (132.919 us; speedup 1.0000x reference)
//
#include <hip/hip_runtime.h>

// Problem constants
static constexpr int NQ    = 12;
static constexpr int DEPTH = 4;
static constexpr int LAT   = 512;
static constexpr int FAST  = DEPTH * NQ;   // 48
static constexpr float DECAY = 0.9f;

// Layout: block = 128 threads = 2 waves = ONE batch element.
// Amplitude index i = h*2048 + lane*32 + r   (h = wave id, lane 6b, r 5b)
// Wire w <-> index bit (11-w):
//   wire 0      -> h (cross-wave)
//   wires 1..6  -> lane bit (6-w)   (M = 32,16,8,4,2,1)
//   wires 7..11 -> r bit (11-w)     (S = 16,8,4,2,1)

__device__ __forceinline__ float i2f(int x) { return __int_as_float(x); }

// VALU-pipe lane-XOR partner fetch.
template<int M>
__device__ __forceinline__ float xpartner(float x, int lane) {
    int xi = __float_as_int(x);
    if constexpr (M == 1) {        // quad_perm [1,0,3,2]
        return i2f(__builtin_amdgcn_update_dpp(xi, xi, 0xB1, 0xF, 0xF, true));
    } else if constexpr (M == 2) { // quad_perm [2,3,0,1]
        return i2f(__builtin_amdgcn_update_dpp(xi, xi, 0x4E, 0xF, 0xF, true));
    } else if constexpr (M == 4) { // row_half_mirror (xor7) then quad reverse (xor3)
        int t = __builtin_amdgcn_update_dpp(xi, xi, 0x141, 0xF, 0xF, true);
        return i2f(__builtin_amdgcn_update_dpp(t, t, 0x1B, 0xF, 0xF, true));
    } else if constexpr (M == 8) { // row_ror:8 == xor8 within 16-lane rows
        return i2f(__builtin_amdgcn_update_dpp(xi, xi, 0x128, 0xF, 0xF, true));
    } else if constexpr (M == 16) {
#if __has_builtin(__builtin_amdgcn_permlane16_swap)
        auto r = __builtin_amdgcn_permlane16_swap((unsigned)xi, (unsigned)xi, false, false);
        return i2f((int)(r[0] ^ r[1]) ^ xi);   // {own,partner} pair -> partner
#else
        return __shfl_xor(x, 16, 64);
#endif
    } else {
#if __has_builtin(__builtin_amdgcn_permlane32_swap)
        auto r = __builtin_amdgcn_permlane32_swap((unsigned)xi, (unsigned)xi, false, false);
        return i2f((int)(r[0] ^ r[1]) ^ xi);
#else
        return __shfl_xor(x, 32, 64);
#endif
    }
}

// RY on lane wire W in [1,6]
template<int W>
__device__ __forceinline__ void ry_lane(float (&v)[32], int lane, float c, float s) {
    constexpr int M = 1 << (6 - W);
    float t = (lane & M) ? s : -s;
    #pragma unroll
    for (int r = 0; r < 32; r++) {
        float p = xpartner<M>(v[r], lane);
        v[r] = c * v[r] + t * p;
    }
}

// RY on register wire W in [7,11]
template<int W>
__device__ __forceinline__ void ry_reg(float (&v)[32], float c, float s) {
    constexpr int S = 1 << (11 - W);
    #pragma unroll
    for (int r0 = 0; r0 < 32; r0++) {
        if ((r0 & S) == 0) {
            float a = v[r0];
            float b = v[r0 + S];
            v[r0]     = c * a - s * b;
            v[r0 + S] = s * a + c * b;
        }
    }
}

// CNOT(W,W+1) for W in [7,10]: compile-time register renames, ~free.
template<int W>
__device__ __forceinline__ void apply_cnot_reg(float (&v)[32]) {
    constexpr int CBS = 1 << (11 - W);
    constexpr int TBS = 1 << (10 - W);
    #pragma unroll
    for (int r = 0; r < 32; r++) {
        if ((r & CBS) != 0 && (r & TBS) == 0) {
            float tmp = v[r];
            v[r]       = v[r | TBS];
            v[r | TBS] = tmp;
        }
    }
}

template<int W>
__device__ __forceinline__ void cnot_reg_chain(float (&v)[32]) {
    if constexpr (W < 11) {
        apply_cnot_reg<W>(v);
        cnot_reg_chain<W + 1>(v);
    }
}

// RYs for wires 1..11 (wire 0 handled by the cross-wave exchange)
template<int W>
__device__ __forceinline__ void layer_rys(float (&v)[32], int lane, const float* ang) {
    if constexpr (W < 12) {
        float hh = 0.5f * ang[W];
        float c = __cosf(hh), s = __sinf(hh);
        if constexpr (W <= 6) ry_lane<W>(v, lane, c, s);
        else                  ry_reg<W>(v, c, s);
        layer_rys<W + 1>(v, lane, ang);
    }
}

__global__ __launch_bounds__(128, 4)
void fwp_kernel(const float* __restrict__ x_t,
                const float* __restrict__ fast_prev,
                const float* __restrict__ W_enc,
                const float* __restrict__ b_enc,
                const float* __restrict__ W_upd,
                const float* __restrict__ b_upd,
                const float* __restrict__ W_ro,
                const float* __restrict__ b_ro,
                float* __restrict__ out_y,
                float* __restrict__ out_fast) {
    const int tid  = threadIdx.x;
    const int lane = tid & 63;
    const int h    = tid >> 6;        // wave-half = wire 0 bit
    const int b    = blockIdx.x;      // one block per batch row

    __shared__ float s_xch[2 * 2048];   // 16 KB cross-wave exchange
    __shared__ float s_lat[LAT];        // 2 KB latent
    __shared__ float s_ang[FAST];
    __shared__ float s_red[FAST][2];
    __shared__ float s_y[2];

    // ---- x broadcast (per wave) ----
    float xr = (lane < NQ) ? x_t[b * NQ + lane] : 0.0f;
    float xa[NQ];
    #pragma unroll
    for (int k = 0; k < NQ; k++) xa[k] = __shfl(xr, k, 64);

    // ---- Phase A: latent = tanh(W_enc@x + b_enc), 4 per thread ----
    #pragma unroll
    for (int t = 0; t < LAT / 128; t++) {
        int j = tid + 128 * t;
        const float4* wr = (const float4*)(W_enc + j * NQ);
        float4 a0 = wr[0], a1 = wr[1], a2 = wr[2];
        float sum = b_enc[j]
            + a0.x * xa[0] + a0.y * xa[1] + a0.z * xa[2]  + a0.w * xa[3]
            + a1.x * xa[4] + a1.y * xa[5] + a1.z * xa[6]  + a1.w * xa[7]
            + a2.x * xa[8] + a2.y * xa[9] + a2.z * xa[10] + a2.w * xa[11];
        s_lat[j] = tanhf(sum);
    }
    __syncthreads();

    // ---- Phase B: 48 rows, each split across the wave pair ----
    if (lane < FAST) {
        const float4* wr = (const float4*)(W_upd + lane * LAT + h * (LAT / 2));
        const float4* lr = (const float4*)(s_lat + h * (LAT / 2));
        float sum = 0.0f;
        #pragma unroll 16
        for (int j = 0; j < LAT / 8; j++) {   // 64 float4 each half
            float4 w4 = wr[j];
            float4 l4 = lr[j];
            sum += w4.x * l4.x + w4.y * l4.y + w4.z * l4.z + w4.w * l4.w;
        }
        s_red[lane][h] = sum;
    }
    __syncthreads();
    if (tid < FAST) {
        float ang = DECAY * fast_prev[b * FAST + tid]
                  + s_red[tid][0] + s_red[tid][1] + b_upd[tid];
        s_ang[tid] = ang;
        out_fast[b * FAST + tid] = ang;
    }
    __syncthreads();

    // ---- closed-form product-state init ----
    float g0[NQ], g1[NQ];
    #pragma unroll
    for (int w = 0; w < NQ; w++) {
        float hh = 0.5f * xa[w];
        float c = __cosf(hh), s = __sinf(hh);
        g0[w] = (c - s) * 0.70710678118654752f;
        g1[w] = (c + s) * 0.70710678118654752f;
    }
    float L = h ? g1[0] : g0[0];
    #pragma unroll
    for (int w = 1; w <= 6; w++)
        L *= ((lane >> (6 - w)) & 1) ? g1[w] : g0[w];

    float v[32];
    v[0] = L;
    #pragma unroll
    for (int w = 7; w < NQ; w++) {
        const int S = 1 << (11 - w);       // 16,8,4,2,1
        #pragma unroll
        for (int r = 0; r < 32; r += 2 * S) {
            v[r + S] = v[r] * g1[w];
            v[r]     = v[r] * g0[w];
        }
    }

    // ---- composed lane permutation source for CNOT(0,1)..(5,6) ----
    // forward: b5'=b5^h, bk'=bk^b(k+1)'  -> inverse: b5=l5^h, bk=lk^l(k+1)
    const int csrc  = ((lane ^ (lane >> 1)) & 31) | ((((lane >> 5) & 1) ^ h) << 5);
    const int csrc4 = csrc << 2;

    // ---- 4 layers ----
    #pragma unroll 1
    for (int layer = 0; layer < DEPTH; layer++) {
        const float* ang = &s_ang[layer * NQ];
        // CNOT(0,1)..(5,6): one composed wave-local gather per register
        #pragma unroll
        for (int r = 0; r < 32; r++)
            v[r] = i2f(__builtin_amdgcn_ds_bpermute(csrc4, __float_as_int(v[r])));
        // CNOT(6,7): control = lane bit0, target = r bit4
        bool cc = (lane & 1) != 0;
        #pragma unroll
        for (int r0 = 0; r0 < 16; r0++) {
            float a = v[r0], bb = v[r0 + 16];
            v[r0]      = cc ? bb : a;
            v[r0 + 16] = cc ? a : bb;
        }
        // CNOT(7,8)..(10,11): free register renames
        cnot_reg_chain<7>(v);

        // RY(0): cross-wave via LDS exchange
        {
            float hh = 0.5f * ang[0];
            float c = __cosf(hh), s = __sinf(hh);
            __syncthreads();   // previous layer's reads done before overwrite
            #pragma unroll
            for (int r = 0; r < 32; r++)
                s_xch[h * 2048 + r * 64 + lane] = v[r];
            __syncthreads();
            float t = h ? s : -s;
            #pragma unroll
            for (int r = 0; r < 32; r++) {
                float p = s_xch[(1 - h) * 2048 + r * 64 + lane];
                v[r] = c * v[r] + t * p;
            }
        }
        // RY(1..11)
        layer_rys<1>(v, lane, ang);
    }

    // ---- Z expectations folded into readout ----
    float tot = 0.0f, pw[5] = {0, 0, 0, 0, 0};
    #pragma unroll
    for (int r = 0; r < 32; r++) {
        float p = v[r] * v[r];
        tot += p;
        pw[0] += (r & 16) ? -p : p;   // wire 7
        pw[1] += (r & 8)  ? -p : p;   // wire 8
        pw[2] += (r & 4)  ? -p : p;   // wire 9
        pw[3] += (r & 2)  ? -p : p;   // wire 10
        pw[4] += (r & 1)  ? -p : p;   // wire 11
    }
    float sl = h ? -W_ro[0] : W_ro[0];
    #pragma unroll
    for (int w = 1; w <= 6; w++) {
        float c = W_ro[w];
        sl += ((lane >> (6 - w)) & 1) ? -c : c;
    }
    float y = sl * tot;
    #pragma unroll
    for (int k = 0; k < 5; k++) y += W_ro[7 + k] * pw[k];
    #pragma unroll
    for (int m = 32; m >= 1; m >>= 1) y += __shfl_xor(y, m, 64);
    if (lane == 0) s_y[h] = y;
    __syncthreads();
    if (tid == 0) out_y[b] = s_y[0] + s_y[1] + b_ro[0];
}

extern "C" void kernel_launch(void* const* d_in, const int* in_sizes, int n_in,
                              void* d_out, int out_size, void* d_ws, size_t ws_size,
                              hipStream_t stream) {
    const float* x_t       = (const float*)d_in[0];
    const float* fast_prev = (const float*)d_in[1];
    const float* W_enc     = (const float*)d_in[2];
    const float* b_enc     = (const float*)d_in[3];
    const float* W_upd     = (const float*)d_in[4];
    const float* b_upd     = (const float*)d_in[5];
    const float* W_ro      = (const float*)d_in[6];
    const float* b_ro      = (const float*)d_in[7];
    float* out = (float*)d_out;

    fwp_kernel<<<2048, 128, 0, stream>>>(x_t, fast_prev, W_enc, b_enc,
                                         W_upd, b_upd, W_ro, b_ro,
                                         out /*y*/, out + 2048 /*fast_next*/);
}

// Round 5
// 115.134 us; speedup vs baseline: 1.1545x; 1.1545x over previous
//
#include <hip/hip_runtime.h>

// Problem constants
static constexpr int NQ    = 12;
static constexpr int DEPTH = 4;
static constexpr int LAT   = 512;
static constexpr int FAST  = DEPTH * NQ;   // 48
static constexpr float DECAY = 0.9f;
static constexpr int PITCH = 65;           // 64 + 1 pad: conflict-free transpose

// One wave = one batch element. 4096 amplitudes in 64 VGPRs/lane.
// L orientation: i = (lane<<6) | r      (wire w <-> bit (11-w))
//   wires 0..5 -> lane bits 5..0, wires 6..11 -> reg bits 5..0
// T orientation: i = (r<<6) | lane      (wires 0..5 -> reg bits, 6..11 -> lane bits)
//
// Layer = RY(all wires) ∘ CNOT-chain(0..10).  CNOT chain is GF(2)-linear:
// sigma: bit'_p = XOR of bits p..11  =>  sigma^-1: bit_p = j_p ^ j_{p+1} (p<=10).
// Pass 1 (LDS round-trip) applies sigma AND flips L->T via read addressing;
// then wires 0..5 are register butterflies. Pass 2 transposes back T->L;
// then wires 6..11 are register butterflies. No DPP/shuffle/bpermute anywhere.

// RY butterfly on register stride S: out0 = c*a - s*b, out1 = s*a + c*b
template<int S>
__device__ __forceinline__ void bfly(float (&v)[64], float c, float s) {
    #pragma unroll
    for (int r0 = 0; r0 < 64; r0++) {
        if ((r0 & S) == 0) {
            float a = v[r0], b = v[r0 + S];
            v[r0]     = c * a - s * b;
            v[r0 + S] = s * a + c * b;
        }
    }
}

// 6 RYs with strides 32,16,8,4,2,1 — used for wires 0..5 (in T) and 6..11 (in L)
template<int K>
__device__ __forceinline__ void ry6(float (&v)[64], const float* lc, const float* ls) {
    if constexpr (K < 6) {
        bfly<(1 << (5 - K))>(v, lc[K], ls[K]);
        ry6<K + 1>(v, lc, ls);
    }
}

__global__ __launch_bounds__(64, 2)
void fwp_kernel(const float* __restrict__ x_t,
                const float* __restrict__ fast_prev,
                const float* __restrict__ W_enc,
                const float* __restrict__ b_enc,
                const float* __restrict__ W_upd,
                const float* __restrict__ b_upd,
                const float* __restrict__ W_ro,
                const float* __restrict__ b_ro,
                float* __restrict__ out_y,
                float* __restrict__ out_fast) {
    const int lane = threadIdx.x;   // block = exactly one wave
    const int b    = blockIdx.x;

    __shared__ __align__(16) float s_xch[64 * PITCH];  // 16.6 KB transpose buffer
    __shared__ float s_c[FAST], s_s[FAST];             // per-gate cos/sin

    float* s_lat = s_xch;   // GEMV latent reuses the buffer (dead before layer 0)

    // ---- x broadcast ----
    float xr = (lane < NQ) ? x_t[b * NQ + lane] : 0.0f;
    float xa[NQ];
    #pragma unroll
    for (int k = 0; k < NQ; k++) xa[k] = __shfl(xr, k, 64);

    // ---- Phase A: latent = tanh(W_enc@x + b_enc), 8 per lane ----
    #pragma unroll
    for (int t = 0; t < LAT / 64; t++) {
        int j = lane + 64 * t;
        const float4* wr = (const float4*)(W_enc + j * NQ);
        float4 a0 = wr[0], a1 = wr[1], a2 = wr[2];
        float sum = b_enc[j]
            + a0.x * xa[0] + a0.y * xa[1] + a0.z * xa[2]  + a0.w * xa[3]
            + a1.x * xa[4] + a1.y * xa[5] + a1.z * xa[6]  + a1.w * xa[7]
            + a2.x * xa[8] + a2.y * xa[9] + a2.z * xa[10] + a2.w * xa[11];
        s_lat[j] = tanhf(sum);
    }
    __syncthreads();

    // ---- Phase B: 48 angles; lane o<48 owns one W_upd row; also cos/sin ----
    if (lane < FAST) {
        const float4* wr = (const float4*)(W_upd + lane * LAT);
        const float4* lr = (const float4*)(s_lat);
        float sum = b_upd[lane];
        #pragma unroll 16
        for (int j = 0; j < LAT / 4; j++) {
            float4 w4 = wr[j];
            float4 l4 = lr[j];   // uniform address -> LDS broadcast
            sum += w4.x * l4.x + w4.y * l4.y + w4.z * l4.z + w4.w * l4.w;
        }
        float ang = DECAY * fast_prev[b * FAST + lane] + sum;
        out_fast[b * FAST + lane] = ang;
        float hh = 0.5f * ang;
        s_c[lane] = __cosf(hh);
        s_s[lane] = __sinf(hh);
    }
    __syncthreads();

    // ---- closed-form product-state init (L orientation) ----
    float g0[NQ], g1[NQ];
    #pragma unroll
    for (int w = 0; w < NQ; w++) {
        float hh = 0.5f * xa[w];
        float c = __cosf(hh), s = __sinf(hh);
        g0[w] = (c - s) * 0.70710678118654752f;
        g1[w] = (c + s) * 0.70710678118654752f;
    }
    float L = 1.0f;
    #pragma unroll
    for (int w = 0; w < 6; w++)
        L *= ((lane >> (5 - w)) & 1) ? g1[w] : g0[w];

    float v[64];
    v[0] = L;
    #pragma unroll
    for (int w = 6; w < NQ; w++) {
        const int S = 1 << (11 - w);
        #pragma unroll
        for (int r = 0; r < 64; r += 2 * S) {
            v[r + S] = v[r] * g1[w];
            v[r]     = v[r] * g0[w];
        }
    }

    // Pass-1 read bases: src reg = pairwise-xor(lane bits) with MSB ^= (r&1)
    const int A0 = ((lane ^ (lane >> 1)) & 31) | (lane & 32);
    const int A1 = A0 ^ 32;

    // ---- 4 layers ----
    #pragma unroll 1
    for (int layer = 0; layer < DEPTH; layer++) {
        const float* lc = &s_c[layer * NQ];
        const float* ls = &s_s[layer * NQ];

        // Pass 1: CNOT chain (sigma) + L->T, folded into addressing
        __syncthreads();                    // WAR: prior reads done before overwrite
        #pragma unroll
        for (int r = 0; r < 64; r++) s_xch[lane * PITCH + r] = v[r];
        __syncthreads();                    // RAW: writes visible
        #pragma unroll
        for (int r = 0; r < 64; r++) {
            const int g = r ^ (r >> 1);     // compile-time: src lane = gray(r)
            v[r] = s_xch[g * PITCH + ((r & 1) ? A1 : A0)];
        }
        // RY wires 0..5 (now register bits, strides 32..1)
        ry6<0>(v, lc, ls);

        // Pass 2: plain transpose T->L
        __syncthreads();                    // WAR
        #pragma unroll
        for (int r = 0; r < 64; r++) s_xch[lane * PITCH + r] = v[r];
        __syncthreads();                    // RAW
        #pragma unroll
        for (int r = 0; r < 64; r++) v[r] = s_xch[r * PITCH + lane];
        // RY wires 6..11 (register bits, strides 32..1)
        ry6<0>(v, lc + 6, ls + 6);
    }

    // ---- Z expectations folded into readout (L orientation) ----
    float tot = 0.0f, pw[6] = {0, 0, 0, 0, 0, 0};
    #pragma unroll
    for (int r = 0; r < 64; r++) {
        float p = v[r] * v[r];
        tot += p;
        pw[0] += (r & 32) ? -p : p;   // wire 6
        pw[1] += (r & 16) ? -p : p;   // wire 7
        pw[2] += (r & 8)  ? -p : p;   // wire 8
        pw[3] += (r & 4)  ? -p : p;   // wire 9
        pw[4] += (r & 2)  ? -p : p;   // wire 10
        pw[5] += (r & 1)  ? -p : p;   // wire 11
    }
    float sl = 0.0f;
    #pragma unroll
    for (int w = 0; w < 6; w++) {
        float c = W_ro[w];
        sl += ((lane >> (5 - w)) & 1) ? -c : c;
    }
    float y = sl * tot;
    #pragma unroll
    for (int k = 0; k < 6; k++) y += W_ro[6 + k] * pw[k];
    #pragma unroll
    for (int m = 32; m >= 1; m >>= 1) y += __shfl_xor(y, m, 64);
    if (lane == 0) out_y[b] = y + b_ro[0];
}

extern "C" void kernel_launch(void* const* d_in, const int* in_sizes, int n_in,
                              void* d_out, int out_size, void* d_ws, size_t ws_size,
                              hipStream_t stream) {
    const float* x_t       = (const float*)d_in[0];
    const float* fast_prev = (const float*)d_in[1];
    const float* W_enc     = (const float*)d_in[2];
    const float* b_enc     = (const float*)d_in[3];
    const float* W_upd     = (const float*)d_in[4];
    const float* b_upd     = (const float*)d_in[5];
    const float* W_ro      = (const float*)d_in[6];
    const float* b_ro      = (const float*)d_in[7];
    float* out = (float*)d_out;

    fwp_kernel<<<2048, 64, 0, stream>>>(x_t, fast_prev, W_enc, b_enc,
                                        W_upd, b_upd, W_ro, b_ro,
                                        out /*y*/, out + 2048 /*fast_next*/);
}